// Round 10
// baseline (171.776 us; speedup 1.0000x reference)
//
#include <hip/hip_runtime.h>
#include <hip/hip_bf16.h>
#include <cstdint>

typedef __attribute__((ext_vector_type(8))) short v8s;   // 8 x bf16 bits (4 VGPRs)
typedef __attribute__((ext_vector_type(4))) float v4f;   // 16B fp32 / MFMA acc

#define NUM_HEADS 8
#define D 256
#define CCH 2048               // channels
#define SEGS 64                // segments (blocks) per head

// float -> bf16 bits, round-to-nearest-even
__device__ __forceinline__ short f2bf(float f) {
  unsigned u = __builtin_bit_cast(unsigned, f);
  u = (u + 0x7FFFu + ((u >> 16) & 1u)) >> 16;
  return (short)u;
}

// ---------------------------------------------------------------------------
// Single-kernel grouped GEMM. 512 blocks (2/CU) x 512 threads (8 waves).
// Block = (head, 24/25-tile segment). Wave wv: ntiles {2wv,2wv+1}.
//
// ROUND-10 CHANGE — pack_w folded away: each wave gathers + converts its own
// B slice (2 ntiles x 8 ksteps = 4 KB bf16) directly from the fp32 weight in
// the prologue. w is 2 MB -> L2/L3-resident after first touch; the gather is
// 128 stride-1KB dword loads per lane (64 B-coalesced per 16-lane group),
// #pragma unroll 2 caps the in-flight window (32 temps) to stay off the
// round-4 VGPR cliff. Removes the serial pack_w kernel + graph gap.
//
// Everything else = round-9 (87 us): reg-staged bf16 A (convert once,
// ds_write_b128), ring-3 8 KB LDS slots, XOR swizzle both-sides
// (elem k of row r at byte r*512 + ((k/8)*16 ^ ((r&7)<<4))), counted
// vmcnt(2), 2-period lookahead, named ping-pong reg sets (rule #20).
// ---------------------------------------------------------------------------
__global__ __launch_bounds__(512, 4) void grouped_mm(const float* __restrict__ x,
                                                     const float* __restrict__ w,
                                                     float* __restrict__ out) {
  __shared__ alignas(16) char As[3][8192];  // ring: bf16 tiles [row16][512B]
  const int tid  = threadIdx.x;
  const int wv   = tid >> 6;          // wave 0..7 = n-group (ntiles 2wv, 2wv+1)
  const int lane = tid & 63;
  const int head = blockIdx.x >> 6;
  const int seg  = blockIdx.x & 63;
  const int t0   = (seg < 32) ? seg * 25 : 800 + (seg - 32) * 24;
  const int nt   = (seg < 32) ? 25 : 24;

  const int row = lane & 15;          // fragment row / n-within-tile
  const int kg  = lane >> 4;          // k subgroup

  // ---- B gather+convert from fp32 weight (one-time; w is L2/L3-resident) --
  // Fragment def: lane holds B[k = s*32 + kg*8 + e][n = j*16 + row], e=0..7.
  v8s Bf0[8], Bf1[8];
  {
    const float* wb = w + (size_t)head * 65536 + (size_t)(kg * 8) * 256 + row;
#pragma unroll 2
    for (int s = 0; s < 8; ++s) {
      const float* ws0 = wb + s * 32 * 256 + (2 * wv) * 16;
      const float* ws1 = ws0 + 16;
      v8s b0, b1;
#pragma unroll
      for (int e = 0; e < 8; ++e) {
        b0[e] = f2bf(ws0[e * 256]);
        b1[e] = f2bf(ws1[e * 256]);
      }
      Bf0[s] = b0;
      Bf1[s] = b1;
    }
  }

  // ---- staging thread coords: thread t covers (srow, 8 consecutive k) ----
  const int srow  = tid >> 5;         // 0..15
  const int skseg = tid & 31;         // 0..31 (k = skseg*8 .. +7)
  const unsigned swoff = (unsigned)(srow * 512)
                       + (((unsigned)(skseg * 16)) ^ ((unsigned)((srow & 7) << 4)));
  const float* xbase = x + (size_t)head * D + (size_t)srow * CCH + skseg * 8;

  // issue global loads for head-local tile t into named regs (32 B/thread)
  auto issue = [&](int t, v4f& g0, v4f& g1) {
    const float* gp = xbase + (size_t)t * 16 * CCH;
    g0 = *reinterpret_cast<const v4f*>(gp);
    g1 = *reinterpret_cast<const v4f*>(gp + 4);
  };
  // convert + write staged regs into ring slot
  auto writeslot = [&](int slot, const v4f& g0, const v4f& g1) {
    v8s wv8;
#pragma unroll
    for (int e = 0; e < 4; ++e) {
      wv8[e]     = f2bf(g0[e]);
      wv8[4 + e] = f2bf(g1[e]);
    }
    *reinterpret_cast<v8s*>(&As[0][0] + slot * 8192 + swoff) = wv8;
  };

  const unsigned rsw = (unsigned)((row & 7) << 4);

  // compute tile p from slot, store
  auto compute = [&](int slot, int p) {
    const char* ar = &As[0][0] + slot * 8192 + row * 512;
    v4f acc0 = (v4f){0.f, 0.f, 0.f, 0.f};
    v4f acc1 = (v4f){0.f, 0.f, 0.f, 0.f};
#pragma unroll
    for (int s = 0; s < 8; ++s) {
      const unsigned off = (((unsigned)((s * 4 + kg) * 16)) ^ rsw);
      v8s af = *reinterpret_cast<const v8s*>(ar + off);
      acc0 = __builtin_amdgcn_mfma_f32_16x16x32_bf16(af, Bf0[s], acc0, 0, 0, 0);
      acc1 = __builtin_amdgcn_mfma_f32_16x16x32_bf16(af, Bf1[s], acc1, 0, 0, 0);
    }
    // C/D layout: col = lane&15, row = kg*4 + r
    float* op = out + (size_t)((t0 + p) * 16 + kg * 4) * CCH
                    + head * D + wv * 32 + row;
#pragma unroll
    for (int r = 0; r < 4; ++r) {
      op[(size_t)r * CCH]      = acc0[r];
      op[(size_t)r * CCH + 16] = acc1[r];
    }
  };

  // ---- prologue: load tiles 0,1; convert tile 0 into slot 0 ----
  v4f A0, A1, B0, B1;                 // two named ping-pong reg sets (rule #20)
  issue(t0 + 0, A0, A1);
  if (nt > 1) issue(t0 + 1, B0, B1);
  asm volatile("s_waitcnt vmcnt(2)" ::: "memory");  // g0 done, g1 in flight
  writeslot(0, A0, A1);
  asm volatile("s_waitcnt lgkmcnt(0)" ::: "memory");
  __builtin_amdgcn_s_barrier();

  // body(p): GI = reg set to issue g_{p+2} into, GC = reg set holding g_{p+1}
#define BODY(p, GI0, GI1, GC0, GC1)                                        \
  {                                                                        \
    const int c = (p) % 3;                                                 \
    int n1 = c + 1; if (n1 >= 3) n1 -= 3;                                  \
    if ((p) + 2 < nt) issue(t0 + (p) + 2, GI0, GI1);                       \
    asm volatile("s_waitcnt vmcnt(2)" ::: "memory");                       \
    if ((p) + 1 < nt) writeslot(n1, GC0, GC1);                             \
    compute(c, (p));                                                       \
    asm volatile("s_waitcnt lgkmcnt(0)" ::: "memory");                     \
    __builtin_amdgcn_s_barrier();                                          \
  }

  for (int p = 0; p < nt; p += 2) {
    BODY(p, A0, A1, B0, B1);                   // even: issue->A, convert B
    if (p + 1 < nt) BODY(p + 1, B0, B1, A0, A1);  // odd: issue->B, convert A
  }
#undef BODY
}

extern "C" void kernel_launch(void* const* d_in, const int* in_sizes, int n_in,
                              void* d_out, int out_size, void* d_ws, size_t ws_size,
                              hipStream_t stream) {
  const float* x = (const float*)d_in[0];   // (8,56,56,2048) fp32
  const float* w = (const float*)d_in[1];   // (8,256,256) fp32
  float* out = (float*)d_out;               // (8,56,56,2048) fp32

  grouped_mm<<<NUM_HEADS * SEGS, 512, 0, stream>>>(x, w, out);
}

// Round 11
// 110.914 us; speedup vs baseline: 1.5487x; 1.5487x over previous
//
#include <hip/hip_runtime.h>
#include <hip/hip_bf16.h>
#include <cstdint>

typedef __attribute__((ext_vector_type(8))) short v8s;   // 8 x bf16 bits (4 VGPRs)
typedef __attribute__((ext_vector_type(4))) float v4f;   // 16B fp32 / MFMA acc

#define NUM_HEADS 8
#define D 256
#define CCH 2048               // channels
#define SEGS 64                // segments (blocks) per head

// float -> bf16 bits, round-to-nearest-even
__device__ __forceinline__ short f2bf(float f) {
  unsigned u = __builtin_bit_cast(unsigned, f);
  u = (u + 0x7FFFu + ((u >> 16) & 1u)) >> 16;
  return (short)u;
}

// ---------------------------------------------------------------------------
// Single-kernel grouped GEMM. 512 blocks (2/CU) x 512 threads (8 waves).
// Block = (head, 24/25-tile segment). Wave wv: ntiles {2wv,2wv+1}.
//
// ROUND-11 FIX of round 10: the B gather loop is FULLY unrolled so every
// Bf0[s]/Bf1[s] index is compile-time constant -> stays in VGPRs. Round 10's
// `#pragma unroll 2` left `s` runtime -> runtime-indexed ext_vector arrays
// -> scratch (rule #20): VGPR_Count=64, B re-read from scratch per tile,
// 172 us. Check VGPR_Count ~110-128 to confirm residency.
//
// Each wave gathers + converts its own B slice (2 ntiles x 8 ksteps = 4 KB
// bf16) directly from the fp32 weight (2 MB, L2/L3-resident after first
// touch); removes the serial pack_w kernel + inter-kernel graph gap.
//
// Everything else = round-9 (87 us): reg-staged bf16 A (convert once,
// ds_write_b128), ring-3 8 KB LDS slots, XOR swizzle both-sides
// (elem k of row r at byte r*512 + ((k/8)*16 ^ ((r&7)<<4))), counted
// vmcnt(2), 2-period lookahead, named ping-pong reg sets.
// ---------------------------------------------------------------------------
__global__ __launch_bounds__(512, 4) void grouped_mm(const float* __restrict__ x,
                                                     const float* __restrict__ w,
                                                     float* __restrict__ out) {
  __shared__ alignas(16) char As[3][8192];  // ring: bf16 tiles [row16][512B]
  const int tid  = threadIdx.x;
  const int wv   = tid >> 6;          // wave 0..7 = n-group (ntiles 2wv, 2wv+1)
  const int lane = tid & 63;
  const int head = blockIdx.x >> 6;
  const int seg  = blockIdx.x & 63;
  const int t0   = (seg < 32) ? seg * 25 : 800 + (seg - 32) * 24;
  const int nt   = (seg < 32) ? 25 : 24;

  const int row = lane & 15;          // fragment row / n-within-tile
  const int kg  = lane >> 4;          // k subgroup

  // ---- B gather+convert from fp32 weight (one-time; w is L2/L3-resident) --
  // Fragment def: lane holds B[k = s*32 + kg*8 + e][n = j*16 + row], e=0..7.
  v8s Bf0[8], Bf1[8];
  {
    const float* wb = w + (size_t)head * 65536 + (size_t)(kg * 8) * 256 + row;
#pragma unroll
    for (int s = 0; s < 8; ++s) {    // FULL unroll: static indices (rule #20)
      const float* ws0 = wb + s * 32 * 256 + (2 * wv) * 16;
      const float* ws1 = ws0 + 16;
      v8s b0, b1;
#pragma unroll
      for (int e = 0; e < 8; ++e) {
        b0[e] = f2bf(ws0[e * 256]);
        b1[e] = f2bf(ws1[e * 256]);
      }
      Bf0[s] = b0;
      Bf1[s] = b1;
    }
  }

  // ---- staging thread coords: thread t covers (srow, 8 consecutive k) ----
  const int srow  = tid >> 5;         // 0..15
  const int skseg = tid & 31;         // 0..31 (k = skseg*8 .. +7)
  const unsigned swoff = (unsigned)(srow * 512)
                       + (((unsigned)(skseg * 16)) ^ ((unsigned)((srow & 7) << 4)));
  const float* xbase = x + (size_t)head * D + (size_t)srow * CCH + skseg * 8;

  // issue global loads for head-local tile t into named regs (32 B/thread)
  auto issue = [&](int t, v4f& g0, v4f& g1) {
    const float* gp = xbase + (size_t)t * 16 * CCH;
    g0 = *reinterpret_cast<const v4f*>(gp);
    g1 = *reinterpret_cast<const v4f*>(gp + 4);
  };
  // convert + write staged regs into ring slot
  auto writeslot = [&](int slot, const v4f& g0, const v4f& g1) {
    v8s wv8;
#pragma unroll
    for (int e = 0; e < 4; ++e) {
      wv8[e]     = f2bf(g0[e]);
      wv8[4 + e] = f2bf(g1[e]);
    }
    *reinterpret_cast<v8s*>(&As[0][0] + slot * 8192 + swoff) = wv8;
  };

  const unsigned rsw = (unsigned)((row & 7) << 4);

  // compute tile p from slot, store
  auto compute = [&](int slot, int p) {
    const char* ar = &As[0][0] + slot * 8192 + row * 512;
    v4f acc0 = (v4f){0.f, 0.f, 0.f, 0.f};
    v4f acc1 = (v4f){0.f, 0.f, 0.f, 0.f};
#pragma unroll
    for (int s = 0; s < 8; ++s) {
      const unsigned off = (((unsigned)((s * 4 + kg) * 16)) ^ rsw);
      v8s af = *reinterpret_cast<const v8s*>(ar + off);
      acc0 = __builtin_amdgcn_mfma_f32_16x16x32_bf16(af, Bf0[s], acc0, 0, 0, 0);
      acc1 = __builtin_amdgcn_mfma_f32_16x16x32_bf16(af, Bf1[s], acc1, 0, 0, 0);
    }
    // C/D layout: col = lane&15, row = kg*4 + r
    float* op = out + (size_t)((t0 + p) * 16 + kg * 4) * CCH
                    + head * D + wv * 32 + row;
#pragma unroll
    for (int r = 0; r < 4; ++r) {
      op[(size_t)r * CCH]      = acc0[r];
      op[(size_t)r * CCH + 16] = acc1[r];
    }
  };

  // ---- prologue: load tiles 0,1; convert tile 0 into slot 0 ----
  v4f A0, A1, B0, B1;                 // two named ping-pong reg sets (rule #20)
  issue(t0 + 0, A0, A1);
  if (nt > 1) issue(t0 + 1, B0, B1);
  asm volatile("s_waitcnt vmcnt(2)" ::: "memory");  // g0 done, g1 in flight
  writeslot(0, A0, A1);
  asm volatile("s_waitcnt lgkmcnt(0)" ::: "memory");
  __builtin_amdgcn_s_barrier();

  // body(p): GI = reg set to issue g_{p+2} into, GC = reg set holding g_{p+1}
#define BODY(p, GI0, GI1, GC0, GC1)                                        \
  {                                                                        \
    const int c = (p) % 3;                                                 \
    int n1 = c + 1; if (n1 >= 3) n1 -= 3;                                  \
    if ((p) + 2 < nt) issue(t0 + (p) + 2, GI0, GI1);                       \
    asm volatile("s_waitcnt vmcnt(2)" ::: "memory");                       \
    if ((p) + 1 < nt) writeslot(n1, GC0, GC1);                             \
    compute(c, (p));                                                       \
    asm volatile("s_waitcnt lgkmcnt(0)" ::: "memory");                     \
    __builtin_amdgcn_s_barrier();                                          \
  }

  for (int p = 0; p < nt; p += 2) {
    BODY(p, A0, A1, B0, B1);                   // even: issue->A, convert B
    if (p + 1 < nt) BODY(p + 1, B0, B1, A0, A1);  // odd: issue->B, convert A
  }
#undef BODY
}

extern "C" void kernel_launch(void* const* d_in, const int* in_sizes, int n_in,
                              void* d_out, int out_size, void* d_ws, size_t ws_size,
                              hipStream_t stream) {
  const float* x = (const float*)d_in[0];   // (8,56,56,2048) fp32
  const float* w = (const float*)d_in[1];   // (8,256,256) fp32
  float* out = (float*)d_out;               // (8,56,56,2048) fp32

  grouped_mm<<<NUM_HEADS * SEGS, 512, 0, stream>>>(x, w, out);
}

// Round 12
// 86.329 us; speedup vs baseline: 1.9898x; 1.2848x over previous
//
#include <hip/hip_runtime.h>
#include <hip/hip_bf16.h>
#include <cstdint>

typedef __attribute__((ext_vector_type(8))) short v8s;   // 8 x bf16 bits (4 VGPRs)
typedef __attribute__((ext_vector_type(4))) float v4f;   // 16B fp32 / MFMA acc

#define NUM_HEADS 8
#define D 256
#define CCH 2048               // channels
#define SEGS 64                // segments (blocks) per head

// float -> bf16 bits, round-to-nearest-even
__device__ __forceinline__ short f2bf(float f) {
  unsigned u = __builtin_bit_cast(unsigned, f);
  u = (u + 0x7FFFu + ((u >> 16) & 1u)) >> 16;
  return (short)u;
}

// ---------------------------------------------------------------------------
// Pack weight (8,256,256) fp32 -> fragment-ordered bf16 in d_ws (1 MiB).
// Unit u = (s*16 + j)*64 + lane within head, 16 B each:
// B[k = s*32 + (lane>>4)*8 + e][n = j*16 + (lane&15)], e = 0..7 — the
// mfma_f32_16x16x32_bf16 B fragment for (kstep s, ntile j).
// NOTE (rounds 10/11): folding this into the main kernel fails — the strided
// fp32 gather under a 128-VGPR budget forces the allocator to spill the B
// fragments to scratch (VGPR_Count=64, 111-172 us). Only packed CONTIGUOUS
// fragment loads stay register-resident in the main kernel.
// ---------------------------------------------------------------------------
__global__ __launch_bounds__(256) void pack_w(const float* __restrict__ w,
                                              short* __restrict__ p) {
  int idx  = blockIdx.x * 256 + threadIdx.x;  // 0..65535
  int lane = idx & 63;
  int j    = (idx >> 6) & 15;
  int s    = (idx >> 10) & 7;
  int head = idx >> 13;
  int n  = j * 16 + (lane & 15);
  int k0 = s * 32 + (lane >> 4) * 8;
  const float* src = w + head * 65536 + k0 * 256 + n;
  v8s v;
#pragma unroll
  for (int e = 0; e < 8; ++e) v[e] = f2bf(src[e * 256]);
  *reinterpret_cast<v8s*>(p + (size_t)idx * 8) = v;
}

// ---------------------------------------------------------------------------
// Main grouped GEMM. 512 blocks (2/CU) x 512 threads (8 waves) = 4 waves/SIMD.
// Block = (head, 24/25-tile segment). Wave wv: ntiles {2wv,2wv+1}, B slice
// register-resident (64 VGPR), loaded once from the packed buffer.
//
// Convert-once bf16 A staging: global fp32 -> VGPR -> f2bf -> ds_write_b128;
// ring-3 8 KB LDS slots; inner loop = 8 x {ds_read_b128 -> MFMA}.
// A-slot layout: elem k of row r at byte r*512 + ((k/8)*16 ^ ((r&7)<<4)),
// writer and reader use the same formula (both-sides rule).
// Pipeline: period p issues loads for tile p+2, converts+writes tile p+1
// into slot (p+1)%3, computes tile p from slot p%3; counted vmcnt(2);
// named ping-pong reg sets (rule #20).
// Session best: 87.0 us (410 MB app traffic -> 4.9 TB/s; 5 structural
// nulls bracket this as the mixed-stream bandwidth floor).
// ---------------------------------------------------------------------------
__global__ __launch_bounds__(512, 4) void grouped_mm(const float* __restrict__ x,
                                                     const short* __restrict__ pB,
                                                     float* __restrict__ out) {
  __shared__ alignas(16) char As[3][8192];  // ring: bf16 tiles [row16][512B]
  const int tid  = threadIdx.x;
  const int wv   = tid >> 6;          // wave 0..7 = n-group (ntiles 2wv, 2wv+1)
  const int lane = tid & 63;
  const int head = blockIdx.x >> 6;
  const int seg  = blockIdx.x & 63;
  const int t0   = (seg < 32) ? seg * 25 : 800 + (seg - 32) * 24;
  const int nt   = (seg < 32) ? 25 : 24;

  const int row = lane & 15;          // fragment row / n-within-tile
  const int kg  = lane >> 4;          // k subgroup

  // ---- persistent B fragments: 2 ntiles x 8 ksteps (64 VGPR) ----
  v8s Bf0[8], Bf1[8];
  {
    const short* pb = pB + (size_t)head * 65536 + (size_t)lane * 8;
#pragma unroll
    for (int s = 0; s < 8; ++s) {
      Bf0[s] = *reinterpret_cast<const v8s*>(pb + (size_t)(s * 16 + 2 * wv)     * 512);
      Bf1[s] = *reinterpret_cast<const v8s*>(pb + (size_t)(s * 16 + 2 * wv + 1) * 512);
    }
  }

  // ---- staging thread coords: thread t covers (srow, 8 consecutive k) ----
  const int srow  = tid >> 5;         // 0..15
  const int skseg = tid & 31;         // 0..31 (k = skseg*8 .. +7)
  const unsigned swoff = (unsigned)(srow * 512)
                       + (((unsigned)(skseg * 16)) ^ ((unsigned)((srow & 7) << 4)));
  const float* xbase = x + (size_t)head * D + (size_t)srow * CCH + skseg * 8;

  // issue global loads for head-local tile t into named regs (32 B/thread)
  auto issue = [&](int t, v4f& g0, v4f& g1) {
    const float* gp = xbase + (size_t)t * 16 * CCH;
    g0 = *reinterpret_cast<const v4f*>(gp);
    g1 = *reinterpret_cast<const v4f*>(gp + 4);
  };
  // convert + write staged regs into ring slot
  auto writeslot = [&](int slot, const v4f& g0, const v4f& g1) {
    v8s wv8;
#pragma unroll
    for (int e = 0; e < 4; ++e) {
      wv8[e]     = f2bf(g0[e]);
      wv8[4 + e] = f2bf(g1[e]);
    }
    *reinterpret_cast<v8s*>(&As[0][0] + slot * 8192 + swoff) = wv8;
  };

  const unsigned rsw = (unsigned)((row & 7) << 4);

  // compute tile p from slot, store
  auto compute = [&](int slot, int p) {
    const char* ar = &As[0][0] + slot * 8192 + row * 512;
    v4f acc0 = (v4f){0.f, 0.f, 0.f, 0.f};
    v4f acc1 = (v4f){0.f, 0.f, 0.f, 0.f};
#pragma unroll
    for (int s = 0; s < 8; ++s) {
      const unsigned off = (((unsigned)((s * 4 + kg) * 16)) ^ rsw);
      v8s af = *reinterpret_cast<const v8s*>(ar + off);
      acc0 = __builtin_amdgcn_mfma_f32_16x16x32_bf16(af, Bf0[s], acc0, 0, 0, 0);
      acc1 = __builtin_amdgcn_mfma_f32_16x16x32_bf16(af, Bf1[s], acc1, 0, 0, 0);
    }
    // C/D layout: col = lane&15, row = kg*4 + r
    float* op = out + (size_t)((t0 + p) * 16 + kg * 4) * CCH
                    + head * D + wv * 32 + row;
#pragma unroll
    for (int r = 0; r < 4; ++r) {
      op[(size_t)r * CCH]      = acc0[r];
      op[(size_t)r * CCH + 16] = acc1[r];
    }
  };

  // ---- prologue: load tiles 0,1; convert tile 0 into slot 0 ----
  v4f A0, A1, B0, B1;                 // two named ping-pong reg sets (rule #20)
  issue(t0 + 0, A0, A1);
  if (nt > 1) issue(t0 + 1, B0, B1);
  asm volatile("s_waitcnt vmcnt(2)" ::: "memory");  // g0 done, g1 in flight
  writeslot(0, A0, A1);
  asm volatile("s_waitcnt lgkmcnt(0)" ::: "memory");
  __builtin_amdgcn_s_barrier();

  // body(p): GI = reg set to issue g_{p+2} into, GC = reg set holding g_{p+1}
#define BODY(p, GI0, GI1, GC0, GC1)                                        \
  {                                                                        \
    const int c = (p) % 3;                                                 \
    int n1 = c + 1; if (n1 >= 3) n1 -= 3;                                  \
    if ((p) + 2 < nt) issue(t0 + (p) + 2, GI0, GI1);                       \
    asm volatile("s_waitcnt vmcnt(2)" ::: "memory");                       \
    if ((p) + 1 < nt) writeslot(n1, GC0, GC1);                             \
    compute(c, (p));                                                       \
    asm volatile("s_waitcnt lgkmcnt(0)" ::: "memory");                     \
    __builtin_amdgcn_s_barrier();                                          \
  }

  for (int p = 0; p < nt; p += 2) {
    BODY(p, A0, A1, B0, B1);                   // even: issue->A, convert B
    if (p + 1 < nt) BODY(p + 1, B0, B1, A0, A1);  // odd: issue->B, convert A
  }
#undef BODY
}

extern "C" void kernel_launch(void* const* d_in, const int* in_sizes, int n_in,
                              void* d_out, int out_size, void* d_ws, size_t ws_size,
                              hipStream_t stream) {
  const float* x = (const float*)d_in[0];   // (8,56,56,2048) fp32
  const float* w = (const float*)d_in[1];   // (8,256,256) fp32
  float* out = (float*)d_out;               // (8,56,56,2048) fp32
  short* packed = (short*)d_ws;             // 1 MiB packed bf16 weights

  pack_w<<<256, 256, 0, stream>>>(w, packed);
  grouped_mm<<<NUM_HEADS * SEGS, 512, 0, stream>>>(x, packed, out);
}